// Round 8
// baseline (2507.016 us; speedup 1.0000x reference)
//
#include <hip/hip_runtime.h>
#include <math.h>

#define BB 128
#define TT 512
#define HH 128
#define G4 512      // 4*H
#define CC 128
#define WW 32
#define NB 16       // batches per block in k1 (MFMA N dimension)

// ---- workspace layout (float slots) ----
#define OFF_FCWT  0                          // 16384
#define OFF_W1P   (OFF_FCWT + CC*HH)         // f16 permuted Whh1: 32768 slots
#define OFF_WI2P  (OFF_W1P  + G4*HH/2)
#define OFF_WH2P  (OFF_WI2P + G4*HH/2)
#define OFF_B1P   (OFF_WH2P + G4*HH/2)       // 512
#define OFF_WI1P  (OFF_B1P + G4)
#define OFF_B2P   (OFF_WI1P + G4)
#define OFF_H2A   (OFF_B2P + G4)             // [T][B][H] fp32 (read-only after k1)
#define OFF_DOLD  (OFF_H2A + TT*BB*HH)
#define OFF_DH    (OFF_DOLD + TT*BB)
#define OFF_MT    (OFF_DH + TT*BB)
#define OFF_ST    (OFF_MT + TT)

typedef _Float16 h2t  __attribute__((ext_vector_type(2)));
typedef _Float16 f16x8 __attribute__((ext_vector_type(8)));
typedef float    f32x4 __attribute__((ext_vector_type(4)));

__device__ __forceinline__ float sigm(float v) {
    return 1.f / (1.f + __expf(-v));
}
__device__ __forceinline__ float ftanh(float v) {
    return 1.f - 2.f / (__expf(2.f * v) + 1.f);
}
__device__ __forceinline__ unsigned short f16b(float v) {
    return __builtin_bit_cast(unsigned short, (_Float16)v);
}

// K0: gate-interleaved (r = h*4 + g) f16 weight images + permuted biases +
// fcW transpose. With this permutation, the MFMA C-layout row (= quad*4+reg)
// gives each lane all 4 gates (i,f,g,o) of one hidden unit in its 4 acc regs.
__global__ __launch_bounds__(256) void k0_prep(
    const float* __restrict__ Whh1, const float* __restrict__ Wih2,
    const float* __restrict__ Whh2, const float* __restrict__ fcW,
    const float* __restrict__ Wih1,
    const float* __restrict__ bih1, const float* __restrict__ bhh1,
    const float* __restrict__ bih2, const float* __restrict__ bhh2,
    float* __restrict__ fcWT,
    unsigned short* __restrict__ w1p, unsigned short* __restrict__ wi2p,
    unsigned short* __restrict__ wh2p,
    float* __restrict__ b1p, float* __restrict__ wi1p, float* __restrict__ b2p)
{
    int idx = blockIdx.x * blockDim.x + threadIdx.x;
    if (idx < G4 * HH) {
        int r_old = idx >> 7, k = idx & 127;
        int g = r_old >> 7, h = r_old & 127;
        int dst = (h * 4 + g) * HH + k;
        w1p [dst] = f16b(Whh1[idx]);
        wi2p[dst] = f16b(Wih2[idx]);
        wh2p[dst] = f16b(Whh2[idx]);
    }
    if (idx < CC * HH) {
        int c = idx / HH, h = idx % HH;
        fcWT[h * CC + c] = fcW[idx];
    }
    if (idx < G4) {
        int g = idx >> 7, h = idx & 127;
        int rn = h * 4 + g;
        b1p [rn] = bih1[idx] + bhh1[idx];
        wi1p[rn] = Wih1[idx];
        b2p [rn] = bih2[idx] + bhh2[idx];
    }
}

// K1: MFMA LSTM. 8 blocks x 512 threads; block owns 16 batches.
// Per step: gates(512x16) = W(512x128) @ state(128x16) via 32 tiles of
// mfma_f32_16x16x32_f16 per matmul (3 matmuls). Weights live in 192
// register dwords/thread as A-fragments (AGPR-friendly: MFMA reads A from
// AGPR natively). State vectors go through LDS in B-fragment order:
// halves[(k>>3)*16 + n][k&7] -> each wave reads contiguous 1KB, and each
// lane's cell results scatter back with b16 writes (2-way conflicts, free).
__global__ __launch_bounds__(512, 2) void k1_lstm(
    const float* __restrict__ x,
    const float* __restrict__ b1p, const float* __restrict__ wi1p,
    const float* __restrict__ b2p,
    const unsigned short* __restrict__ w1p,
    const unsigned short* __restrict__ wi2p,
    const unsigned short* __restrict__ wh2p,
    float* __restrict__ h2a)
{
    __shared__ __align__(16) unsigned short h1f[2][2048];
    __shared__ __align__(16) unsigned short c1f[2][2048];
    __shared__ __align__(16) unsigned short h2f[2][2048];
    __shared__ float xs[TT][NB];

    const int tid  = threadIdx.x;
    const int gb0  = blockIdx.x * NB;
    const int w    = tid >> 6;      // wave 0..7: gate rows [w*64, w*64+64)
    const int lane = tid & 63;
    const int n    = lane & 15;     // B-operand col / C col (batch)
    const int qd   = lane >> 4;     // quad

    // stage x transposed: xs[t][batch]
    for (int i = tid; i < NB * TT; i += 512) {
        int bi = i >> 9, ti = i & 511;
        xs[ti][bi] = x[(size_t)(gb0 + bi) * TT + ti];
    }
    // zero parity-0 state (t=0 reads zeros -> uniform loop, no prologue)
    for (int i = tid; i < 1024; i += 512) {
        ((unsigned int*)&h1f[0][0])[i] = 0u;
        ((unsigned int*)&c1f[0][0])[i] = 0u;
        ((unsigned int*)&h2f[0][0])[i] = 0u;
    }

    // ---- A-fragments: lane holds A[m=lane&15][k=qd*8+j] of each 16x32 chunk
    f16x8 w1A[4][4], wi2A[4][4], wh2A[4][4];
    #pragma unroll
    for (int tt = 0; tt < 4; ++tt) {
        const int row = w * 64 + tt * 16 + n;     // here lane&15 = tile row m
        #pragma unroll
        for (int kc = 0; kc < 4; ++kc) {
            const size_t off = (size_t)row * HH + kc * 32 + qd * 8;
            w1A [tt][kc] = *(const f16x8*)(w1p  + off);
            wi2A[tt][kc] = *(const f16x8*)(wi2p + off);
            wh2A[tt][kc] = *(const f16x8*)(wh2p + off);
        }
    }
    // ---- packed biases: acc reg r covers permuted row rb+r (C-layout) ----
    unsigned int pb1wi[4][4];   // (b1, wi1) f16 pair per (tile, reg)
    unsigned int pb2[4][2];     // (b2[2r], b2[2r+1]) pairs
    #pragma unroll
    for (int tt = 0; tt < 4; ++tt) {
        const int rb = w * 64 + tt * 16 + qd * 4;
        #pragma unroll
        for (int r = 0; r < 4; ++r) {
            h2t pv; pv.x = (_Float16)b1p[rb + r]; pv.y = (_Float16)wi1p[rb + r];
            pb1wi[tt][r] = __builtin_bit_cast(unsigned int, pv);
        }
        #pragma unroll
        for (int r = 0; r < 2; ++r) {
            h2t pv; pv.x = (_Float16)b2p[rb + 2 * r]; pv.y = (_Float16)b2p[rb + 2 * r + 1];
            pb2[tt][r] = __builtin_bit_cast(unsigned int, pv);
        }
    }
    float c1s[4] = {0.f, 0.f, 0.f, 0.f};
    float c2s[4] = {0.f, 0.f, 0.f, 0.f};
    __syncthreads();

    for (int t = 0; t < TT; ++t) {
        const int p = t & 1, q = p ^ 1;
        const float xv = xs[t][n];

        // ---- phase A: layer-1 gates + cells ----
        f32x4 acc[4];
        #pragma unroll
        for (int tt = 0; tt < 4; ++tt) {
            #pragma unroll
            for (int r = 0; r < 4; ++r) {
                h2t bw = __builtin_bit_cast(h2t, pb1wi[tt][r]);
                acc[tt][r] = (float)bw.x + (float)bw.y * xv;
            }
        }
        #pragma unroll
        for (int kc = 0; kc < 4; ++kc) {
            f16x8 hb = *(const f16x8*)&h1f[p][((kc * 4 + qd) * 16 + n) * 8];
            #pragma unroll
            for (int tt = 0; tt < 4; ++tt)
                acc[tt] = __builtin_amdgcn_mfma_f32_16x16x32_f16(
                    w1A[tt][kc], hb, acc[tt], 0, 0, 0);
        }
        #pragma unroll
        for (int tt = 0; tt < 4; ++tt) {
            float cn = sigm(acc[tt][1]) * c1s[tt] + sigm(acc[tt][0]) * ftanh(acc[tt][2]);
            c1s[tt] = cn;
            float hn = sigm(acc[tt][3]) * ftanh(cn);
            int u = w * 16 + tt * 4 + qd;
            int pos = (((u >> 3) * 16 + n) << 3) + (u & 7);
            h1f[q][pos] = f16b(hn);
            c1f[q][pos] = f16b(cn);
        }
        __syncthreads();

        // ---- phase B: layer-2 gates + cells (input c1(t), recurrent h2(t-1))
        #pragma unroll
        for (int tt = 0; tt < 4; ++tt) {
            #pragma unroll
            for (int r = 0; r < 2; ++r) {
                h2t bw = __builtin_bit_cast(h2t, pb2[tt][r]);
                acc[tt][2 * r]     = (float)bw.x;
                acc[tt][2 * r + 1] = (float)bw.y;
            }
        }
        #pragma unroll
        for (int kc = 0; kc < 4; ++kc) {
            f16x8 cb = *(const f16x8*)&c1f[q][((kc * 4 + qd) * 16 + n) * 8];
            #pragma unroll
            for (int tt = 0; tt < 4; ++tt)
                acc[tt] = __builtin_amdgcn_mfma_f32_16x16x32_f16(
                    wi2A[tt][kc], cb, acc[tt], 0, 0, 0);
        }
        #pragma unroll
        for (int kc = 0; kc < 4; ++kc) {
            f16x8 gb = *(const f16x8*)&h2f[p][((kc * 4 + qd) * 16 + n) * 8];
            #pragma unroll
            for (int tt = 0; tt < 4; ++tt)
                acc[tt] = __builtin_amdgcn_mfma_f32_16x16x32_f16(
                    wh2A[tt][kc], gb, acc[tt], 0, 0, 0);
        }
        #pragma unroll
        for (int tt = 0; tt < 4; ++tt) {
            float cn = sigm(acc[tt][1]) * c2s[tt] + sigm(acc[tt][0]) * ftanh(acc[tt][2]);
            c2s[tt] = cn;
            float hn = sigm(acc[tt][3]) * ftanh(cn);
            int u = w * 16 + tt * 4 + qd;
            int pos = (((u >> 3) * 16 + n) << 3) + (u & 7);
            h2f[q][pos] = f16b(hn);
            h2a[(size_t)t * (BB * HH) + (size_t)(gb0 + n) * HH + u] = hn;
        }
        __syncthreads();
    }
}

// K2: d_old[t,b] = h2[t,b,:].wt_old ; d_h[t,b] = h2[t,b,:].wt_h
__global__ __launch_bounds__(256) void k2_dots(
    const float* __restrict__ h2a, const float* __restrict__ w_t,
    float* __restrict__ dold, float* __restrict__ dh)
{
    const int lane = threadIdx.x & 63;
    const int wave = blockIdx.x * (blockDim.x >> 6) + (threadIdx.x >> 6);
    const int nw = gridDim.x * (blockDim.x >> 6);
    const float wh0 = w_t[lane],       wh1 = w_t[64 + lane];
    const float wo0 = w_t[128 + lane], wo1 = w_t[192 + lane];
    for (int row = wave; row < TT * BB; row += nw) {
        const float* p = h2a + (size_t)row * HH;
        float v0 = p[lane], v1 = p[64 + lane];
        float po = v0 * wo0 + v1 * wo1;
        float ph = v0 * wh0 + v1 * wh1;
        #pragma unroll
        for (int off = 32; off; off >>= 1) {
            po += __shfl_xor(po, off);
            ph += __shfl_xor(ph, off);
        }
        if (lane == 0) { dold[row] = po; dh[row] = ph; }
    }
}

// K3: per-t global softmax stats over valid (j,b): m[t], s[t]
__global__ __launch_bounds__(256) void k3_stats(
    const float* __restrict__ dold, const float* __restrict__ dh,
    float* __restrict__ mt, float* __restrict__ st)
{
    const int t = blockIdx.x;
    const int tid = threadIdx.x;
    const int cnt = (min(t, WW) + 1) * BB;
    const int jstart = max(t - (WW + 1), -1);

    float m = -INFINITY;
    for (int idx = tid; idx < cnt; idx += 256) {
        int jj = idx >> 7, b = idx & 127;
        int j = jstart + jj;
        float sc = dh[t * BB + b] + (j >= 0 ? dold[j * BB + b] : 0.f);
        m = fmaxf(m, sc);
    }
    #pragma unroll
    for (int off = 32; off; off >>= 1) m = fmaxf(m, __shfl_xor(m, off));
    __shared__ float rbuf[4];
    int wv = tid >> 6, ln = tid & 63;
    if (ln == 0) rbuf[wv] = m;
    __syncthreads();
    m = fmaxf(fmaxf(rbuf[0], rbuf[1]), fmaxf(rbuf[2], rbuf[3]));

    float s = 0.f;
    for (int idx = tid; idx < cnt; idx += 256) {
        int jj = idx >> 7, b = idx & 127;
        int j = jstart + jj;
        float sc = dh[t * BB + b] + (j >= 0 ? dold[j * BB + b] : 0.f);
        s += __expf(sc - m);
    }
    #pragma unroll
    for (int off = 32; off; off >>= 1) s += __shfl_xor(s, off);
    __shared__ float sbuf[4];
    if (ln == 0) sbuf[wv] = s;
    __syncthreads();
    if (tid == 0) { mt[t] = m; st[t] = sbuf[0] + sbuf[1] + sbuf[2] + sbuf[3]; }
}

// K45: fused attention + FC. grid (TT/8, BB), block 256.
__global__ __launch_bounds__(256) void k45_attn_fc(
    const float* __restrict__ h2a,
    const float* __restrict__ dold, const float* __restrict__ dh,
    const float* __restrict__ mt, const float* __restrict__ st,
    const float* __restrict__ fcWT, const float* __restrict__ fcb,
    float* __restrict__ out)
{
    const int t0 = blockIdx.x * 8;
    const int b  = blockIdx.y;
    const int tid = threadIdx.x;

    __shared__ float hbuf[41][HH];     // rows t0-33 .. t0+7
    __shared__ float wjs[8][36];
    __shared__ float ytile[8][HH];

    for (int i = tid; i < 41 * 32; i += 256) {
        int r = i >> 5, q4 = i & 31;
        int t = t0 - 33 + r;
        float4 v = make_float4(0.f, 0.f, 0.f, 0.f);
        if (t >= 0)
            v = *(const float4*)(h2a + (size_t)t * (BB * HH) + (size_t)b * HH + q4 * 4);
        *(float4*)&hbuf[r][q4 * 4] = v;
    }
    for (int i = tid; i < 8 * 33; i += 256) {
        int tt = i / 33, ss = i % 33;
        int t = t0 + tt, j = t - 33 + ss;
        float w = 0.f;
        if (j >= 0)
            w = __expf(dold[j * BB + b] + dh[t * BB + b] - mt[t]) / st[t];
        wjs[tt][ss] = w;
    }
    __syncthreads();

    {
        const int tq = tid >> 5;
        const int hq = (tid & 31) * 4;
        float4 acc = *(const float4*)&hbuf[tq + 33][hq];   // h2[t]
        #pragma unroll 11
        for (int ss = 0; ss < 33; ++ss) {
            float w = wjs[tq][ss];
            float4 hb = *(const float4*)&hbuf[tq + ss][hq];
            acc.x = fmaf(w, hb.x, acc.x);
            acc.y = fmaf(w, hb.y, acc.y);
            acc.z = fmaf(w, hb.z, acc.z);
            acc.w = fmaf(w, hb.w, acc.w);
        }
        *(float4*)&ytile[tq][hq] = acc;
    }
    __syncthreads();

    {
        const int c  = tid & 127;
        const int th = tid >> 7;
        float acc[4];
        const float bias = fcb[c];
        #pragma unroll
        for (int i = 0; i < 4; ++i) acc[i] = bias;
        for (int hh = 0; hh < HH; ++hh) {
            float w = fcWT[hh * CC + c];
            #pragma unroll
            for (int i = 0; i < 4; ++i)
                acc[i] = fmaf(ytile[th * 4 + i][hh], w, acc[i]);
        }
        #pragma unroll
        for (int i = 0; i < 4; ++i) {
            int t = t0 + th * 4 + i;
            out[(size_t)b * (TT * CC) + (size_t)t * CC + c] = acc[i];
        }
    }
}

extern "C" void kernel_launch(void* const* d_in, const int* in_sizes, int n_in,
                              void* d_out, int out_size, void* d_ws, size_t ws_size,
                              hipStream_t stream)
{
    const float* x    = (const float*)d_in[0];
    const float* Wih1 = (const float*)d_in[1];
    const float* Whh1 = (const float*)d_in[2];
    const float* bih1 = (const float*)d_in[3];
    const float* bhh1 = (const float*)d_in[4];
    const float* Wih2 = (const float*)d_in[5];
    const float* Whh2 = (const float*)d_in[6];
    const float* bih2 = (const float*)d_in[7];
    const float* bhh2 = (const float*)d_in[8];
    const float* w_t  = (const float*)d_in[9];
    const float* fcW  = (const float*)d_in[10];
    const float* fcb  = (const float*)d_in[11];
    float* out = (float*)d_out;

    float* ws   = (float*)d_ws;
    float* fcWT = ws + OFF_FCWT;
    unsigned short* w1p  = (unsigned short*)(ws + OFF_W1P);
    unsigned short* wi2p = (unsigned short*)(ws + OFF_WI2P);
    unsigned short* wh2p = (unsigned short*)(ws + OFF_WH2P);
    float* b1pp = ws + OFF_B1P;
    float* wi1p = ws + OFF_WI1P;
    float* b2pp = ws + OFF_B2P;
    float* h2a  = ws + OFF_H2A;
    float* dold = ws + OFF_DOLD;
    float* dh   = ws + OFF_DH;
    float* mt   = ws + OFF_MT;
    float* st   = ws + OFF_ST;

    k0_prep<<<dim3((G4 * HH + 255) / 256), dim3(256), 0, stream>>>(
        Whh1, Wih2, Whh2, fcW, Wih1, bih1, bhh1, bih2, bhh2,
        fcWT, w1p, wi2p, wh2p, b1pp, wi1p, b2pp);

    k1_lstm<<<dim3(BB / NB), dim3(512), 0, stream>>>(
        x, b1pp, wi1p, b2pp, w1p, wi2p, wh2p, h2a);

    k2_dots<<<dim3(256), dim3(256), 0, stream>>>(h2a, w_t, dold, dh);

    k3_stats<<<dim3(TT), dim3(256), 0, stream>>>(dold, dh, mt, st);

    k45_attn_fc<<<dim3(TT / 8, BB), dim3(256), 0, stream>>>(
        h2a, dold, dh, mt, st, fcWT, fcb, out);
}

// Round 9
// 1154.025 us; speedup vs baseline: 2.1724x; 2.1724x over previous
//
#include <hip/hip_runtime.h>
#include <math.h>

#define BB 128
#define TT 512
#define HH 128
#define G4 512      // 4*H
#define CC 128
#define WW 32

// ---- workspace layout (float slots) ----
#define OFF_FCWT  0                          // 16384
#define OFF_W1P   (OFF_FCWT + CC*HH)         // f16 permuted Whh1: 32768 slots
#define OFF_WI2P  (OFF_W1P  + G4*HH/2)
#define OFF_WH2P  (OFF_WI2P + G4*HH/2)
#define OFF_B1P   (OFF_WH2P + G4*HH/2)       // 512
#define OFF_WI1P  (OFF_B1P + G4)
#define OFF_B2P   (OFF_WI1P + G4)
#define OFF_H2A   (OFF_B2P + G4)             // [T][B][H] fp32 (read-only after k1)
#define OFF_DOLD  (OFF_H2A + TT*BB*HH)
#define OFF_DH    (OFF_DOLD + TT*BB)
#define OFF_MT    (OFF_DH + TT*BB)
#define OFF_ST    (OFF_MT + TT)

typedef _Float16 h2t __attribute__((ext_vector_type(2)));

__device__ __forceinline__ float sigm(float v) {
    return 1.f / (1.f + __expf(-v));
}
__device__ __forceinline__ float ftanh(float v) {
    return 1.f - 2.f / (__expf(2.f * v) + 1.f);
}
__device__ __forceinline__ unsigned short f16b(float v) {
    return __builtin_bit_cast(unsigned short, (_Float16)v);
}
// Guaranteed single-instruction packed-f16 dot2 with fp32 accumulate.
// (R6 evidence: the __builtin_amdgcn_fdot2 path compiled to scalar
// cvt+fma -- ~850 VALU instr/wave/step instead of ~300.)
__device__ __forceinline__ float dot2f(unsigned int a, unsigned int b, float acc) {
    asm("v_dot2_f32_f16 %0, %1, %2, %0" : "+v"(acc) : "v"(a), "v"(b));
    return acc;
}

// K0: gate-interleaved (r = h*4 + g) f16 weight images + permuted biases +
// fcW transpose.
__global__ __launch_bounds__(256) void k0_prep(
    const float* __restrict__ Whh1, const float* __restrict__ Wih2,
    const float* __restrict__ Whh2, const float* __restrict__ fcW,
    const float* __restrict__ Wih1,
    const float* __restrict__ bih1, const float* __restrict__ bhh1,
    const float* __restrict__ bih2, const float* __restrict__ bhh2,
    float* __restrict__ fcWT,
    unsigned short* __restrict__ w1p, unsigned short* __restrict__ wi2p,
    unsigned short* __restrict__ wh2p,
    float* __restrict__ b1p, float* __restrict__ wi1p, float* __restrict__ b2p)
{
    int idx = blockIdx.x * blockDim.x + threadIdx.x;
    if (idx < G4 * HH) {
        int r_old = idx >> 7, k = idx & 127;
        int g = r_old >> 7, h = r_old & 127;
        int dst = (h * 4 + g) * HH + k;
        w1p [dst] = f16b(Whh1[idx]);
        wi2p[dst] = f16b(Wih2[idx]);
        wh2p[dst] = f16b(Whh2[idx]);
    }
    if (idx < CC * HH) {
        int c = idx / HH, h = idx % HH;
        fcWT[h * CC + c] = fcW[idx];
    }
    if (idx < G4) {
        int g = idx >> 7, h = idx & 127;
        int rn = h * 4 + g;
        b1p [rn] = bih1[idx] + bhh1[idx];
        wi1p[rn] = Wih1[idx];
        b2p [rn] = bih2[idx] + bhh2[idx];
    }
}

// K1: software-pipelined all-VGPR-weight LSTM. 128 blocks x 512 threads.
// launch_bounds(512,1): VGPR cap 256 -> 192 weight dwords + temps fit in
// VGPRs, no AGPR round-trips. 8 waves/block = 2 waves/SIMD regardless.
// Thread (r4 = tid>>2, s = tid&3) owns gates i,f,g,o of unit r4 over
// k-slice [32s,32s+32). Layer-2 lags one step; ONE barrier per step.
__global__ __launch_bounds__(512, 1) void k1_lstm(
    const float* __restrict__ x,
    const float* __restrict__ b1p, const float* __restrict__ wi1p,
    const float* __restrict__ b2p,
    const unsigned short* __restrict__ w1p,
    const unsigned short* __restrict__ wi2p,
    const unsigned short* __restrict__ wh2p,
    float* __restrict__ h2a)
{
    __shared__ __align__(16) unsigned int h1h[2][64];
    __shared__ __align__(16) unsigned int c1h[2][64];
    __shared__ __align__(16) unsigned int h2h[2][64];
    __shared__ float xs[TT];

    const int tid = threadIdx.x;
    const int b   = blockIdx.x;
    const int r4  = tid >> 2;       // hidden unit 0..127
    const int s   = tid & 3;        // k-slice: halves [32s, 32s+32)
    const int rbase = r4 * 4;

    // ---- weights: rows rbase..rbase+3, slice s -> 48 uint4 = 192 regs ----
    uint4 w1[4][4], wi2[4][4], wh2[4][4];
    #pragma unroll
    for (int rr = 0; rr < 4; ++rr) {
        const uint4* p1 = (const uint4*)(w1p  + (size_t)(rbase + rr) * HH + 32 * s);
        const uint4* p2 = (const uint4*)(wi2p + (size_t)(rbase + rr) * HH + 32 * s);
        const uint4* p3 = (const uint4*)(wh2p + (size_t)(rbase + rr) * HH + 32 * s);
        #pragma unroll
        for (int q = 0; q < 4; ++q) { w1[rr][q] = p1[q]; wi2[rr][q] = p2[q]; wh2[rr][q] = p3[q]; }
    }
    float b1v[4], wi1v[4], b2v[4];
    #pragma unroll
    for (int rr = 0; rr < 4; ++rr) {
        b1v[rr]  = b1p [rbase + rr];
        wi1v[rr] = wi1p[rbase + rr];
        b2v[rr]  = b2p [rbase + rr];
    }

    xs[tid] = x[(size_t)b * TT + tid];
    if (tid < 64) {
        h1h[0][tid] = 0u; c1h[0][tid] = 0u; h2h[0][tid] = 0u;
        h1h[1][tid] = 0u; c1h[1][tid] = 0u; h2h[1][tid] = 0u;
    }
    float c1reg = 0.f, c2reg = 0.f;
    __syncthreads();

    float* outp = h2a + (size_t)b * HH + r4;

    // ---- prologue u=0: layer-1 only, h1(prev)=0 -> gates are scalar ----
    {
        const float xv = xs[0];
        float gi = fmaf(xv, wi1v[0], b1v[0]);
        float gf = fmaf(xv, wi1v[1], b1v[1]);
        float gg = fmaf(xv, wi1v[2], b1v[2]);
        float go = fmaf(xv, wi1v[3], b1v[3]);
        float cn = sigm(gf) * 0.f + sigm(gi) * ftanh(gg);
        c1reg = cn;
        float hn = sigm(go) * ftanh(cn);
        if (s == 0) {                     // q for u=0 is 1
            ((unsigned short*)&h1h[1][0])[r4] = f16b(hn);
            ((unsigned short*)&c1h[1][0])[r4] = f16b(cn);
        }
    }
    __syncthreads();

    // ---- main: u = 1 .. TT-1 ----
    for (int u = 1; u < TT; ++u) {
        const int p = u & 1, q = p ^ 1;
        const float xv = xs[u];

        // dots layer-1 (t=u): h1h[p] = h1(u-1)
        float a0 = 0.f, a1 = 0.f, a2 = 0.f, a3 = 0.f;
        {
            #pragma unroll
            for (int qq = 0; qq < 4; ++qq) {
                uint4 h4 = *(const uint4*)&h1h[p][16 * s + 4 * qq];
                a0 = dot2f(w1[0][qq].x, h4.x, a0); a0 = dot2f(w1[0][qq].y, h4.y, a0);
                a0 = dot2f(w1[0][qq].z, h4.z, a0); a0 = dot2f(w1[0][qq].w, h4.w, a0);
                a1 = dot2f(w1[1][qq].x, h4.x, a1); a1 = dot2f(w1[1][qq].y, h4.y, a1);
                a1 = dot2f(w1[1][qq].z, h4.z, a1); a1 = dot2f(w1[1][qq].w, h4.w, a1);
                a2 = dot2f(w1[2][qq].x, h4.x, a2); a2 = dot2f(w1[2][qq].y, h4.y, a2);
                a2 = dot2f(w1[2][qq].z, h4.z, a2); a2 = dot2f(w1[2][qq].w, h4.w, a2);
                a3 = dot2f(w1[3][qq].x, h4.x, a3); a3 = dot2f(w1[3][qq].y, h4.y, a3);
                a3 = dot2f(w1[3][qq].z, h4.z, a3); a3 = dot2f(w1[3][qq].w, h4.w, a3);
            }
        }
        // dots layer-2 (t=u-1): c1h[p] = c1(u-1), h2h[p] = h2(u-2)
        float d0 = 0.f, d1 = 0.f, d2 = 0.f, d3 = 0.f;
        {
            #pragma unroll
            for (int qq = 0; qq < 4; ++qq) {
                uint4 c4 = *(const uint4*)&c1h[p][16 * s + 4 * qq];
                uint4 h4 = *(const uint4*)&h2h[p][16 * s + 4 * qq];
                d0 = dot2f(wi2[0][qq].x, c4.x, d0); d0 = dot2f(wh2[0][qq].x, h4.x, d0);
                d0 = dot2f(wi2[0][qq].y, c4.y, d0); d0 = dot2f(wh2[0][qq].y, h4.y, d0);
                d0 = dot2f(wi2[0][qq].z, c4.z, d0); d0 = dot2f(wh2[0][qq].z, h4.z, d0);
                d0 = dot2f(wi2[0][qq].w, c4.w, d0); d0 = dot2f(wh2[0][qq].w, h4.w, d0);
                d1 = dot2f(wi2[1][qq].x, c4.x, d1); d1 = dot2f(wh2[1][qq].x, h4.x, d1);
                d1 = dot2f(wi2[1][qq].y, c4.y, d1); d1 = dot2f(wh2[1][qq].y, h4.y, d1);
                d1 = dot2f(wi2[1][qq].z, c4.z, d1); d1 = dot2f(wh2[1][qq].z, h4.z, d1);
                d1 = dot2f(wi2[1][qq].w, c4.w, d1); d1 = dot2f(wh2[1][qq].w, h4.w, d1);
                d2 = dot2f(wi2[2][qq].x, c4.x, d2); d2 = dot2f(wh2[2][qq].x, h4.x, d2);
                d2 = dot2f(wi2[2][qq].y, c4.y, d2); d2 = dot2f(wh2[2][qq].y, h4.y, d2);
                d2 = dot2f(wi2[2][qq].z, c4.z, d2); d2 = dot2f(wh2[2][qq].z, h4.z, d2);
                d2 = dot2f(wi2[2][qq].w, c4.w, d2); d2 = dot2f(wh2[2][qq].w, h4.w, d2);
                d3 = dot2f(wi2[3][qq].x, c4.x, d3); d3 = dot2f(wh2[3][qq].x, h4.x, d3);
                d3 = dot2f(wi2[3][qq].y, c4.y, d3); d3 = dot2f(wh2[3][qq].y, h4.y, d3);
                d3 = dot2f(wi2[3][qq].z, c4.z, d3); d3 = dot2f(wh2[3][qq].z, h4.z, d3);
                d3 = dot2f(wi2[3][qq].w, c4.w, d3); d3 = dot2f(wh2[3][qq].w, h4.w, d3);
            }
        }
        // quad reductions (8 accs)
        a0 += __shfl_xor(a0, 1); a0 += __shfl_xor(a0, 2);
        a1 += __shfl_xor(a1, 1); a1 += __shfl_xor(a1, 2);
        a2 += __shfl_xor(a2, 1); a2 += __shfl_xor(a2, 2);
        a3 += __shfl_xor(a3, 1); a3 += __shfl_xor(a3, 2);
        d0 += __shfl_xor(d0, 1); d0 += __shfl_xor(d0, 2);
        d1 += __shfl_xor(d1, 1); d1 += __shfl_xor(d1, 2);
        d2 += __shfl_xor(d2, 1); d2 += __shfl_xor(d2, 2);
        d3 += __shfl_xor(d3, 1); d3 += __shfl_xor(d3, 2);

        // cell-1 (t=u)
        {
            float gi = a0 + fmaf(xv, wi1v[0], b1v[0]);
            float gf = a1 + fmaf(xv, wi1v[1], b1v[1]);
            float gg = a2 + fmaf(xv, wi1v[2], b1v[2]);
            float go = a3 + fmaf(xv, wi1v[3], b1v[3]);
            float cn = sigm(gf) * c1reg + sigm(gi) * ftanh(gg);
            c1reg = cn;
            float hn = sigm(go) * ftanh(cn);
            if (s == 0) {
                ((unsigned short*)&h1h[q][0])[r4] = f16b(hn);
                ((unsigned short*)&c1h[q][0])[r4] = f16b(cn);
            }
        }
        // cell-2 (t=u-1)
        {
            float gi = d0 + b2v[0];
            float gf = d1 + b2v[1];
            float gg = d2 + b2v[2];
            float go = d3 + b2v[3];
            float cn = sigm(gf) * c2reg + sigm(gi) * ftanh(gg);
            c2reg = cn;
            float hn = sigm(go) * ftanh(cn);
            if (s == 0) {
                ((unsigned short*)&h2h[q][0])[r4] = f16b(hn);
                outp[(size_t)(u - 1) * (BB * HH)] = hn;
            }
        }
        __syncthreads();
    }

    // ---- epilogue u=TT: layer-2 only (t=TT-1). p = TT&1 = 0 ----
    {
        float d0 = 0.f, d1 = 0.f, d2 = 0.f, d3 = 0.f;
        #pragma unroll
        for (int qq = 0; qq < 4; ++qq) {
            uint4 c4 = *(const uint4*)&c1h[0][16 * s + 4 * qq];
            uint4 h4 = *(const uint4*)&h2h[0][16 * s + 4 * qq];
            d0 = dot2f(wi2[0][qq].x, c4.x, d0); d0 = dot2f(wh2[0][qq].x, h4.x, d0);
            d0 = dot2f(wi2[0][qq].y, c4.y, d0); d0 = dot2f(wh2[0][qq].y, h4.y, d0);
            d0 = dot2f(wi2[0][qq].z, c4.z, d0); d0 = dot2f(wh2[0][qq].z, h4.z, d0);
            d0 = dot2f(wi2[0][qq].w, c4.w, d0); d0 = dot2f(wh2[0][qq].w, h4.w, d0);
            d1 = dot2f(wi2[1][qq].x, c4.x, d1); d1 = dot2f(wh2[1][qq].x, h4.x, d1);
            d1 = dot2f(wi2[1][qq].y, c4.y, d1); d1 = dot2f(wh2[1][qq].y, h4.y, d1);
            d1 = dot2f(wi2[1][qq].z, c4.z, d1); d1 = dot2f(wh2[1][qq].z, h4.z, d1);
            d1 = dot2f(wi2[1][qq].w, c4.w, d1); d1 = dot2f(wh2[1][qq].w, h4.w, d1);
            d2 = dot2f(wi2[2][qq].x, c4.x, d2); d2 = dot2f(wh2[2][qq].x, h4.x, d2);
            d2 = dot2f(wi2[2][qq].y, c4.y, d2); d2 = dot2f(wh2[2][qq].y, h4.y, d2);
            d2 = dot2f(wi2[2][qq].z, c4.z, d2); d2 = dot2f(wh2[2][qq].z, h4.z, d2);
            d2 = dot2f(wi2[2][qq].w, c4.w, d2); d2 = dot2f(wh2[2][qq].w, h4.w, d2);
            d3 = dot2f(wi2[3][qq].x, c4.x, d3); d3 = dot2f(wh2[3][qq].x, h4.x, d3);
            d3 = dot2f(wi2[3][qq].y, c4.y, d3); d3 = dot2f(wh2[3][qq].y, h4.y, d3);
            d3 = dot2f(wi2[3][qq].z, c4.z, d3); d3 = dot2f(wh2[3][qq].z, h4.z, d3);
            d3 = dot2f(wi2[3][qq].w, c4.w, d3); d3 = dot2f(wh2[3][qq].w, h4.w, d3);
        }
        d0 += __shfl_xor(d0, 1); d0 += __shfl_xor(d0, 2);
        d1 += __shfl_xor(d1, 1); d1 += __shfl_xor(d1, 2);
        d2 += __shfl_xor(d2, 1); d2 += __shfl_xor(d2, 2);
        d3 += __shfl_xor(d3, 1); d3 += __shfl_xor(d3, 2);
        float gi = d0 + b2v[0];
        float gf = d1 + b2v[1];
        float gg = d2 + b2v[2];
        float go = d3 + b2v[3];
        float cn = sigm(gf) * c2reg + sigm(gi) * ftanh(gg);
        float hn = sigm(go) * ftanh(cn);
        if (s == 0) outp[(size_t)(TT - 1) * (BB * HH)] = hn;
    }
}

// K2: d_old[t,b] = h2[t,b,:].wt_old ; d_h[t,b] = h2[t,b,:].wt_h
__global__ __launch_bounds__(256) void k2_dots(
    const float* __restrict__ h2a, const float* __restrict__ w_t,
    float* __restrict__ dold, float* __restrict__ dh)
{
    const int lane = threadIdx.x & 63;
    const int wave = blockIdx.x * (blockDim.x >> 6) + (threadIdx.x >> 6);
    const int nw = gridDim.x * (blockDim.x >> 6);
    const float wh0 = w_t[lane],       wh1 = w_t[64 + lane];
    const float wo0 = w_t[128 + lane], wo1 = w_t[192 + lane];
    for (int row = wave; row < TT * BB; row += nw) {
        const float* p = h2a + (size_t)row * HH;
        float v0 = p[lane], v1 = p[64 + lane];
        float po = v0 * wo0 + v1 * wo1;
        float ph = v0 * wh0 + v1 * wh1;
        #pragma unroll
        for (int off = 32; off; off >>= 1) {
            po += __shfl_xor(po, off);
            ph += __shfl_xor(ph, off);
        }
        if (lane == 0) { dold[row] = po; dh[row] = ph; }
    }
}

// K3: per-t global softmax stats over valid (j,b): m[t], s[t]
__global__ __launch_bounds__(256) void k3_stats(
    const float* __restrict__ dold, const float* __restrict__ dh,
    float* __restrict__ mt, float* __restrict__ st)
{
    const int t = blockIdx.x;
    const int tid = threadIdx.x;
    const int cnt = (min(t, WW) + 1) * BB;
    const int jstart = max(t - (WW + 1), -1);

    float m = -INFINITY;
    for (int idx = tid; idx < cnt; idx += 256) {
        int jj = idx >> 7, b = idx & 127;
        int j = jstart + jj;
        float sc = dh[t * BB + b] + (j >= 0 ? dold[j * BB + b] : 0.f);
        m = fmaxf(m, sc);
    }
    #pragma unroll
    for (int off = 32; off; off >>= 1) m = fmaxf(m, __shfl_xor(m, off));
    __shared__ float rbuf[4];
    int wv = tid >> 6, ln = tid & 63;
    if (ln == 0) rbuf[wv] = m;
    __syncthreads();
    m = fmaxf(fmaxf(rbuf[0], rbuf[1]), fmaxf(rbuf[2], rbuf[3]));

    float s = 0.f;
    for (int idx = tid; idx < cnt; idx += 256) {
        int jj = idx >> 7, b = idx & 127;
        int j = jstart + jj;
        float sc = dh[t * BB + b] + (j >= 0 ? dold[j * BB + b] : 0.f);
        s += __expf(sc - m);
    }
    #pragma unroll
    for (int off = 32; off; off >>= 1) s += __shfl_xor(s, off);
    __shared__ float sbuf[4];
    if (ln == 0) sbuf[wv] = s;
    __syncthreads();
    if (tid == 0) { mt[t] = m; st[t] = sbuf[0] + sbuf[1] + sbuf[2] + sbuf[3]; }
}

// K45: fused attention + FC. grid (TT/8, BB), block 256.
__global__ __launch_bounds__(256) void k45_attn_fc(
    const float* __restrict__ h2a,
    const float* __restrict__ dold, const float* __restrict__ dh,
    const float* __restrict__ mt, const float* __restrict__ st,
    const float* __restrict__ fcWT, const float* __restrict__ fcb,
    float* __restrict__ out)
{
    const int t0 = blockIdx.x * 8;
    const int b  = blockIdx.y;
    const int tid = threadIdx.x;

    __shared__ float hbuf[41][HH];     // rows t0-33 .. t0+7
    __shared__ float wjs[8][36];
    __shared__ float ytile[8][HH];

    for (int i = tid; i < 41 * 32; i += 256) {
        int r = i >> 5, q4 = i & 31;
        int t = t0 - 33 + r;
        float4 v = make_float4(0.f, 0.f, 0.f, 0.f);
        if (t >= 0)
            v = *(const float4*)(h2a + (size_t)t * (BB * HH) + (size_t)b * HH + q4 * 4);
        *(float4*)&hbuf[r][q4 * 4] = v;
    }
    for (int i = tid; i < 8 * 33; i += 256) {
        int tt = i / 33, ss = i % 33;
        int t = t0 + tt, j = t - 33 + ss;
        float w = 0.f;
        if (j >= 0)
            w = __expf(dold[j * BB + b] + dh[t * BB + b] - mt[t]) / st[t];
        wjs[tt][ss] = w;
    }
    __syncthreads();

    {
        const int tq = tid >> 5;
        const int hq = (tid & 31) * 4;
        float4 acc = *(const float4*)&hbuf[tq + 33][hq];   // h2[t]
        #pragma unroll 11
        for (int ss = 0; ss < 33; ++ss) {
            float w = wjs[tq][ss];
            float4 hb = *(const float4*)&hbuf[tq + ss][hq];
            acc.x = fmaf(w, hb.x, acc.x);
            acc.y = fmaf(w, hb.y, acc.y);
            acc.z = fmaf(w, hb.z, acc.z);
            acc.w = fmaf(w, hb.w, acc.w);
        }
        *(float4*)&ytile[tq][hq] = acc;
    }
    __syncthreads();

    {
        const int c  = tid & 127;
        const int th = tid >> 7;
        float acc[4];
        const float bias = fcb[c];
        #pragma unroll
        for (int i = 0; i < 4; ++i) acc[i] = bias;
        for (int hh = 0; hh < HH; ++hh) {
            float w = fcWT[hh * CC + c];
            #pragma unroll
            for (int i = 0; i < 4; ++i)
                acc[i] = fmaf(ytile[th * 4 + i][hh], w, acc[i]);
        }
        #pragma unroll
        for (int i = 0; i < 4; ++i) {
            int t = t0 + th * 4 + i;
            out[(size_t)b * (TT * CC) + (size_t)t * CC + c] = acc[i];
        }
    }
}

extern "C" void kernel_launch(void* const* d_in, const int* in_sizes, int n_in,
                              void* d_out, int out_size, void* d_ws, size_t ws_size,
                              hipStream_t stream)
{
    const float* x    = (const float*)d_in[0];
    const float* Wih1 = (const float*)d_in[1];
    const float* Whh1 = (const float*)d_in[2];
    const float* bih1 = (const float*)d_in[3];
    const float* bhh1 = (const float*)d_in[4];
    const float* Wih2 = (const float*)d_in[5];
    const float* Whh2 = (const float*)d_in[6];
    const float* bih2 = (const float*)d_in[7];
    const float* bhh2 = (const float*)d_in[8];
    const float* w_t  = (const float*)d_in[9];
    const float* fcW  = (const float*)d_in[10];
    const float* fcb  = (const float*)d_in[11];
    float* out = (float*)d_out;

    float* ws   = (float*)d_ws;
    float* fcWT = ws + OFF_FCWT;
    unsigned short* w1p  = (unsigned short*)(ws + OFF_W1P);
    unsigned short* wi2p = (unsigned short*)(ws + OFF_WI2P);
    unsigned short* wh2p = (unsigned short*)(ws + OFF_WH2P);
    float* b1pp = ws + OFF_B1P;
    float* wi1p = ws + OFF_WI1P;
    float* b2pp = ws + OFF_B2P;
    float* h2a  = ws + OFF_H2A;
    float* dold = ws + OFF_DOLD;
    float* dh   = ws + OFF_DH;
    float* mt   = ws + OFF_MT;
    float* st   = ws + OFF_ST;

    k0_prep<<<dim3((G4 * HH + 255) / 256), dim3(256), 0, stream>>>(
        Whh1, Wih2, Whh2, fcW, Wih1, bih1, bhh1, bih2, bhh2,
        fcWT, w1p, wi2p, wh2p, b1pp, wi1p, b2pp);

    k1_lstm<<<dim3(BB), dim3(512), 0, stream>>>(
        x, b1pp, wi1p, b2pp, w1p, wi2p, wh2p, h2a);

    k2_dots<<<dim3(256), dim3(256), 0, stream>>>(h2a, w_t, dold, dh);

    k3_stats<<<dim3(TT), dim3(256), 0, stream>>>(dold, dh, mt, st);

    k45_attn_fc<<<dim3(TT / 8, BB), dim3(256), 0, stream>>>(
        h2a, dold, dh, mt, st, fcWT, fcb, out);
}